// Round 2
// baseline (7329.411 us; speedup 1.0000x reference)
//
#include <hip/hip_runtime.h>
#include <cfloat>

// VQ-VAE nearest-codebook quantization.
// N=32768 rows, K=8192 codebook entries, D=64.
// d_out layout (all f32): [0,NQ) quantized, [NQ] vq_loss, [NQ+1] commitment_loss,
//                         [NQ+2, NQ+2+N) encoding_indices (stored as float values).
// d_ws layout (f32): [0,K) codebook squared norms, [K] loss accumulator.

constexpr int N_ROWS = 32768;
constexpr int K_CB   = 8192;
constexpr int D_DIM  = 64;
constexpr size_t NQ  = (size_t)N_ROWS * D_DIM;   // 2097152

// ---------------------------------------------------------------- prep kernel
__global__ __launch_bounds__(256) void vq_prep(const float* __restrict__ cb,
                                               float* __restrict__ ws) {
  const int k = blockIdx.x * 256 + threadIdx.x;
  if (blockIdx.x == 0 && threadIdx.x == 0) ws[K_CB] = 0.0f;  // loss accumulator
  if (k < K_CB) {
    const float4* c4 = reinterpret_cast<const float4*>(cb) + (size_t)k * 16;
    float sx = 0.f, sy = 0.f, sz = 0.f, sw = 0.f;
#pragma unroll
    for (int j = 0; j < 16; ++j) {
      float4 c = c4[j];
      sx = fmaf(c.x, c.x, sx);
      sy = fmaf(c.y, c.y, sy);
      sz = fmaf(c.z, c.z, sz);
      sw = fmaf(c.w, c.w, sw);
    }
    ws[k] = (sx + sy) + (sz + sw);
  }
}

// ---------------------------------------------------------------- main kernel
// Block = 256 threads = 64 rows x 4 K-partitions.
// Thread (row, p) scans codebook entries [p*2048, (p+1)*2048).
__global__ __launch_bounds__(256) void vq_main(const float* __restrict__ z,
                                               const float* __restrict__ cb,
                                               float* __restrict__ ws,
                                               float* __restrict__ out) {
  const int tid = threadIdx.x;
  const int row = blockIdx.x * 64 + (tid >> 2);
  const int p   = tid & 3;

  // Load this thread's z row into registers (16 x float4 = 64 f32).
  const float4* z4 = reinterpret_cast<const float4*>(z) + (size_t)row * 16;
  float4 zr[16];
#pragma unroll
  for (int j = 0; j < 16; ++j) zr[j] = z4[j];

  // ||z||^2 (tree-combined for low rounding error; constant per row but kept
  // to mirror the reference formula d2 = z2 - 2*dot + r2).
  float z2;
  {
    float sx = 0.f, sy = 0.f, sz = 0.f, sw = 0.f;
#pragma unroll
    for (int j = 0; j < 16; ++j) {
      sx = fmaf(zr[j].x, zr[j].x, sx);
      sy = fmaf(zr[j].y, zr[j].y, sy);
      sz = fmaf(zr[j].z, zr[j].z, sz);
      sw = fmaf(zr[j].w, zr[j].w, sw);
    }
    z2 = (sx + sy) + (sz + sw);
  }

  const float4* cb4 = reinterpret_cast<const float4*>(cb);
  float best = FLT_MAX;
  int   bidx = 0;
  const int k0 = p * (K_CB / 4);
  const int k1 = k0 + (K_CB / 4);

#pragma unroll 2
  for (int k = k0; k < k1; ++k) {
    const float4* c = cb4 + (size_t)k * 16;
    // 16 independent FMA chains (4 x float4), tree-combined -> dot error ~2e-5.
    float4 a0 = {0.f, 0.f, 0.f, 0.f};
    float4 a1 = a0, a2 = a0, a3 = a0;
#pragma unroll
    for (int j = 0; j < 16; j += 4) {
      float4 c0 = c[j], c1 = c[j + 1], c2 = c[j + 2], c3 = c[j + 3];
      a0.x = fmaf(zr[j].x, c0.x, a0.x);
      a0.y = fmaf(zr[j].y, c0.y, a0.y);
      a0.z = fmaf(zr[j].z, c0.z, a0.z);
      a0.w = fmaf(zr[j].w, c0.w, a0.w);
      a1.x = fmaf(zr[j + 1].x, c1.x, a1.x);
      a1.y = fmaf(zr[j + 1].y, c1.y, a1.y);
      a1.z = fmaf(zr[j + 1].z, c1.z, a1.z);
      a1.w = fmaf(zr[j + 1].w, c1.w, a1.w);
      a2.x = fmaf(zr[j + 2].x, c2.x, a2.x);
      a2.y = fmaf(zr[j + 2].y, c2.y, a2.y);
      a2.z = fmaf(zr[j + 2].z, c2.z, a2.z);
      a2.w = fmaf(zr[j + 2].w, c2.w, a2.w);
      a3.x = fmaf(zr[j + 3].x, c3.x, a3.x);
      a3.y = fmaf(zr[j + 3].y, c3.y, a3.y);
      a3.z = fmaf(zr[j + 3].z, c3.z, a3.z);
      a3.w = fmaf(zr[j + 3].w, c3.w, a3.w);
    }
    float sxx = (a0.x + a1.x) + (a2.x + a3.x);
    float syy = (a0.y + a1.y) + (a2.y + a3.y);
    float szz = (a0.z + a1.z) + (a2.z + a3.z);
    float sww = (a0.w + a1.w) + (a2.w + a3.w);
    float dot = (sxx + syy) + (szz + sww);
    float d2  = fmaf(-2.f, dot, z2 + ws[k]);
    if (d2 < best) { best = d2; bidx = k; }  // strict < -> first occurrence
  }

  // Merge the 4 K-partitions (lanes tid&~3 .. tid|3 are in the same wave).
#pragma unroll
  for (int off = 1; off < 4; off <<= 1) {
    float ob = __shfl_xor(best, off, 64);
    int   oi = __shfl_xor(bidx, off, 64);
    if (ob < best || (ob == best && oi < bidx)) { best = ob; bidx = oi; }
  }

  // Winner lane: gather codebook row, write quantized + index, loss partial.
  float lpart = 0.f;
  if (p == 0) {
    const float4* q4 = cb4 + (size_t)bidx * 16;
    float4* o4 = reinterpret_cast<float4*>(out) + (size_t)row * 16;
#pragma unroll
    for (int j = 0; j < 16; ++j) {
      float4 q = q4[j];
      o4[j] = q;
      float dx = zr[j].x - q.x, dy = zr[j].y - q.y;
      float dz = zr[j].z - q.z, dw = zr[j].w - q.w;
      lpart += (dx * dx + dy * dy) + (dz * dz + dw * dw);
    }
    out[NQ + 2 + row] = (float)bidx;
  }

  // Wave-reduce loss partial, one atomic per wave.
#pragma unroll
  for (int off = 32; off > 0; off >>= 1) lpart += __shfl_down(lpart, off, 64);
  if ((tid & 63) == 0) atomicAdd(ws + K_CB, lpart);
}

// ------------------------------------------------------------ finalize kernel
__global__ void vq_fin(const float* __restrict__ ws, float* __restrict__ out) {
  float m = ws[K_CB] * (1.0f / (float)(N_ROWS * D_DIM));
  out[NQ]     = m;  // vq_loss
  out[NQ + 1] = m;  // commitment_loss (numerically identical)
}

// -------------------------------------------------------------------- launch
extern "C" void kernel_launch(void* const* d_in, const int* in_sizes, int n_in,
                              void* d_out, int out_size, void* d_ws, size_t ws_size,
                              hipStream_t stream) {
  (void)in_sizes; (void)n_in; (void)out_size; (void)ws_size;
  const float* z  = (const float*)d_in[0];
  const float* cb = (const float*)d_in[1];
  float* out = (float*)d_out;
  float* ws  = (float*)d_ws;

  vq_prep<<<K_CB / 256, 256, 0, stream>>>(cb, ws);
  vq_main<<<N_ROWS / 64, 256, 0, stream>>>(z, cb, ws, out);
  vq_fin<<<1, 1, 0, stream>>>(ws, out);
}

// Round 3
// 485.815 us; speedup vs baseline: 15.0869x; 15.0869x over previous
//
#include <hip/hip_runtime.h>
#include <cfloat>

// VQ-VAE nearest-codebook quantization, register-blocked LDS-tiled version.
// N=32768 rows, K=8192 codes, D=64, all f32.
// d_out (f32): [0,NQ) quantized | [NQ] vq_loss | [NQ+1] commitment_loss |
//              [NQ+2, NQ+2+N) encoding_indices (as float)
// d_ws  (f32): [0,K) r2 | [K, K+N) z2 | [K+N] loss accumulator

constexpr int N_ROWS = 32768;
constexpr int K_CB   = 8192;
constexpr int D_DIM  = 64;
constexpr size_t NQ  = (size_t)N_ROWS * D_DIM;
constexpr int WS_Z2   = K_CB;
constexpr int WS_LOSS = K_CB + N_ROWS;

// ---------------------------------------------------------------- prep kernel
// grid 128x256 = 32768 threads: z2 for every row; r2 for k<8192; zero loss acc.
__global__ __launch_bounds__(256) void vq_prep(const float* __restrict__ z,
                                               const float* __restrict__ cb,
                                               float* __restrict__ ws) {
  const int n = blockIdx.x * 256 + threadIdx.x;
  if (n == 0) ws[WS_LOSS] = 0.0f;
  {
    const float4* p = reinterpret_cast<const float4*>(z) + (size_t)n * 16;
    float s0 = 0.f, s1 = 0.f, s2 = 0.f, s3 = 0.f;
#pragma unroll
    for (int j = 0; j < 16; ++j) {
      float4 v = p[j];
      s0 = fmaf(v.x, v.x, s0); s1 = fmaf(v.y, v.y, s1);
      s2 = fmaf(v.z, v.z, s2); s3 = fmaf(v.w, v.w, s3);
    }
    ws[WS_Z2 + n] = (s0 + s1) + (s2 + s3);
  }
  if (n < K_CB) {
    const float4* p = reinterpret_cast<const float4*>(cb) + (size_t)n * 16;
    float s0 = 0.f, s1 = 0.f, s2 = 0.f, s3 = 0.f;
#pragma unroll
    for (int j = 0; j < 16; ++j) {
      float4 v = p[j];
      s0 = fmaf(v.x, v.x, s0); s1 = fmaf(v.y, v.y, s1);
      s2 = fmaf(v.z, v.z, s2); s3 = fmaf(v.w, v.w, s3);
    }
    ws[n] = (s0 + s1) + (s2 + s3);
  }
}

// ---------------------------------------------------------------- main kernel
// Block: 256 thr = 8 row-groups (i=tid>>5) x 32 k-groups (j=tid&31).
// Covers 64 rows; K in tiles of 256. Thread tile: 8 rows x 8 ks (acc[8][8]).
// LDS transposed: cbt[d][k] and zt[d][row] -> contiguous ds_read_b128.
__global__ __launch_bounds__(256) void vq_main(const float* __restrict__ z,
                                               const float* __restrict__ cb,
                                               float* __restrict__ ws,
                                               float* __restrict__ out) {
  __shared__ float cbt[D_DIM][256];  // 64 KB
  __shared__ float zt[D_DIM][64];    // 16 KB  (total 80 KB -> 2 blocks/CU)

  const int tid = threadIdx.x;
  const int i = tid >> 5;   // 0..7
  const int j = tid & 31;   // 0..31
  const int rowBase = blockIdx.x * 64;

  // Stage z tile transposed (once). Threads 0..63: one row each.
  if (tid < 64) {
    const float4* zp = reinterpret_cast<const float4*>(z) + (size_t)(rowBase + tid) * 16;
#pragma unroll
    for (int c = 0; c < 16; ++c) {
      float4 v = zp[c];
      zt[c * 4 + 0][tid] = v.x;
      zt[c * 4 + 1][tid] = v.y;
      zt[c * 4 + 2][tid] = v.z;
      zt[c * 4 + 3][tid] = v.w;
    }
  }

  // z2 for my 8 rows (from ws, L2-hot).
  float z2r[8];
  {
    const float4* p = reinterpret_cast<const float4*>(ws + WS_Z2 + rowBase + i * 8);
    float4 a = p[0], b = p[1];
    z2r[0] = a.x; z2r[1] = a.y; z2r[2] = a.z; z2r[3] = a.w;
    z2r[4] = b.x; z2r[5] = b.y; z2r[6] = b.z; z2r[7] = b.w;
  }

  float best[8];
  int   bidx[8];
#pragma unroll
  for (int m = 0; m < 8; ++m) { best[m] = FLT_MAX; bidx[m] = 0; }

  for (int tile = 0; tile < K_CB; tile += 256) {
    // r2 for my 8 ks this tile: ks {tile+4j..+3} and {tile+128+4j..+3}.
    float4 r2a = *reinterpret_cast<const float4*>(ws + tile + 4 * j);
    float4 r2b = *reinterpret_cast<const float4*>(ws + tile + 128 + 4 * j);

    // Stage cb tile transposed: thread stages row k = tile + tid.
    const float4* cp = reinterpret_cast<const float4*>(cb) + (size_t)(tile + tid) * 16;
    __syncthreads();  // previous tile's reads done
#pragma unroll
    for (int c = 0; c < 16; ++c) {
      float4 v = cp[c];
      cbt[c * 4 + 0][tid] = v.x;
      cbt[c * 4 + 1][tid] = v.y;
      cbt[c * 4 + 2][tid] = v.z;
      cbt[c * 4 + 3][tid] = v.w;
    }
    __syncthreads();

    float acc[8][8];
#pragma unroll
    for (int m = 0; m < 8; ++m)
#pragma unroll
      for (int kk = 0; kk < 8; ++kk) acc[m][kk] = 0.f;

#pragma unroll 2
    for (int d = 0; d < D_DIM; ++d) {
      float4 ca = *reinterpret_cast<const float4*>(&cbt[d][4 * j]);
      float4 cc = *reinterpret_cast<const float4*>(&cbt[d][128 + 4 * j]);
      float4 za = *reinterpret_cast<const float4*>(&zt[d][i * 8]);
      float4 zb = *reinterpret_cast<const float4*>(&zt[d][i * 8 + 4]);
      float zv[8] = {za.x, za.y, za.z, za.w, zb.x, zb.y, zb.z, zb.w};
      float cv[8] = {ca.x, ca.y, ca.z, ca.w, cc.x, cc.y, cc.z, cc.w};
#pragma unroll
      for (int m = 0; m < 8; ++m)
#pragma unroll
        for (int kk = 0; kk < 8; ++kk)
          acc[m][kk] = fmaf(zv[m], cv[kk], acc[m][kk]);
    }

    // d2 + argmin update. Ascending global k within thread; strict < keeps
    // first occurrence (matches jnp.argmin).
    float r2v[8] = {r2a.x, r2a.y, r2a.z, r2a.w, r2b.x, r2b.y, r2b.z, r2b.w};
    const int kb_lo = tile + 4 * j;
    const int kb_hi = tile + 128 + 4 * j;
#pragma unroll
    for (int m = 0; m < 8; ++m) {
#pragma unroll
      for (int kk = 0; kk < 8; ++kk) {
        float d2 = fmaf(-2.f, acc[m][kk], z2r[m] + r2v[kk]);
        int kg = (kk < 4) ? (kb_lo + kk) : (kb_hi + kk - 4);
        if (d2 < best[m]) { best[m] = d2; bidx[m] = kg; }
      }
    }
  }

  // Merge across the 32 j-lanes (same i). Smaller d2 wins; tie -> smaller k.
#pragma unroll
  for (int off = 1; off <= 16; off <<= 1) {
#pragma unroll
    for (int m = 0; m < 8; ++m) {
      float ob = __shfl_xor(best[m], off, 64);
      int   oi = __shfl_xor(bidx[m], off, 64);
      if (ob < best[m] || (ob == best[m] && oi < bidx[m])) {
        best[m] = ob; bidx[m] = oi;
      }
    }
  }

  // Output: 4 lanes per row. Lane j -> row m=j>>2, chunks (j&3)*4..+3.
  const int m  = j >> 2;
  int idx = bidx[0];
#pragma unroll
  for (int t = 1; t < 8; ++t) idx = (m == t) ? bidx[t] : idx;

  const int row = rowBase + i * 8 + m;
  const int c0  = (j & 3) * 4;
  const float4* qp = reinterpret_cast<const float4*>(cb) + (size_t)idx * 16 + c0;
  const float4* zp = reinterpret_cast<const float4*>(z) + (size_t)row * 16 + c0;
  float4*       op = reinterpret_cast<float4*>(out) + (size_t)row * 16 + c0;
  float lp = 0.f;
#pragma unroll
  for (int c = 0; c < 4; ++c) {
    float4 q = qp[c], zv = zp[c];
    op[c] = q;
    float dx = zv.x - q.x, dy = zv.y - q.y;
    float dz = zv.z - q.z, dw = zv.w - q.w;
    lp += (dx * dx + dy * dy) + (dz * dz + dw * dw);
  }
  if ((j & 3) == 0) out[NQ + 2 + row] = (float)idx;

#pragma unroll
  for (int off = 32; off > 0; off >>= 1) lp += __shfl_down(lp, off, 64);
  if ((tid & 63) == 0) atomicAdd(ws + WS_LOSS, lp);
}

// ------------------------------------------------------------ finalize kernel
__global__ void vq_fin(const float* __restrict__ ws, float* __restrict__ out) {
  float mm = ws[WS_LOSS] * (1.0f / (float)(N_ROWS * D_DIM));
  out[NQ]     = mm;  // vq_loss
  out[NQ + 1] = mm;  // commitment_loss
}

// -------------------------------------------------------------------- launch
extern "C" void kernel_launch(void* const* d_in, const int* in_sizes, int n_in,
                              void* d_out, int out_size, void* d_ws, size_t ws_size,
                              hipStream_t stream) {
  (void)in_sizes; (void)n_in; (void)out_size; (void)ws_size;
  const float* z  = (const float*)d_in[0];
  const float* cb = (const float*)d_in[1];
  float* out = (float*)d_out;
  float* ws  = (float*)d_ws;

  vq_prep<<<N_ROWS / 256, 256, 0, stream>>>(z, cb, ws);
  vq_main<<<N_ROWS / 64, 256, 0, stream>>>(z, cb, ws, out);
  vq_fin<<<1, 1, 0, stream>>>(ws, out);
}

// Round 4
// 172.877 us; speedup vs baseline: 42.3967x; 2.8102x over previous
//
#include <hip/hip_runtime.h>
#include <cfloat>

// VQ-VAE nearest-codebook via bf16x3 split MFMA (32x32x16).
// N=32768 rows, K=8192 codes, D=64, f32 in/out.
// d_out (f32): [0,NQ) quantized | [NQ] vq_loss | [NQ+1] commitment_loss |
//              [NQ+2,NQ+2+N) indices (as float)
// d_ws  (f32): [0,K) r2 | [K] loss accumulator

typedef __bf16 bf16x8 __attribute__((ext_vector_type(8)));
typedef float  f32x16 __attribute__((ext_vector_type(16)));

constexpr int N_ROWS = 32768;
constexpr int K_CB   = 8192;
constexpr int D_DIM  = 64;
constexpr size_t NQ  = (size_t)N_ROWS * D_DIM;
constexpr int WS_LOSS = K_CB;
constexpr int NROUND  = K_CB / 64;   // 128 rounds of 64 codes (2 tiles of 32)

// ---------------------------------------------------------------- prep kernel
__global__ __launch_bounds__(256) void vq_prep(const float* __restrict__ cb,
                                               float* __restrict__ ws) {
  const int k = blockIdx.x * 256 + threadIdx.x;
  if (k == 0) ws[WS_LOSS] = 0.0f;
  const float4* p = reinterpret_cast<const float4*>(cb) + (size_t)k * 16;
  float s0 = 0.f, s1 = 0.f, s2 = 0.f, s3 = 0.f;
#pragma unroll
  for (int j = 0; j < 16; ++j) {
    float4 v = p[j];
    s0 = fmaf(v.x, v.x, s0); s1 = fmaf(v.y, v.y, s1);
    s2 = fmaf(v.z, v.z, s2); s3 = fmaf(v.w, v.w, s3);
  }
  ws[k] = (s0 + s1) + (s2 + s3);
}

// ---------------------------------------------------------------- main kernel
// 512 thr = 8 waves: rg=w>>1 (row group of 32), sp=w&1 (code-split).
// Per round: stage 64 codes (tiles 2r, 2r+1) as bf16 hi/lo into LDS (dbuf),
// each wave computes one 32x32 C-tile (codes x rows) via 12 MFMAs.
// LDS tile layout: [t01][h][chunk=d/8][code] x 16B  -> conflict-free b128 R/W.
__global__ __launch_bounds__(512, 2) void vq_main(const float* __restrict__ z,
                                                  const float* __restrict__ cb,
                                                  float* __restrict__ ws,
                                                  float* __restrict__ out) {
  __shared__ __attribute__((aligned(16))) unsigned char lds[65536];

  const int tid = threadIdx.x;
  const int w = tid >> 6, l = tid & 63;
  const int rg = w >> 1, sp = w & 1;
  const int c = l & 31, g = l >> 5;
  const int rowbase = blockIdx.x * 128;
  const int myrow = rowbase + rg * 32 + c;

  // --- z fragments (hi/lo split), held in registers for the whole kernel ---
  bf16x8 zh[4], zl[4];
#pragma unroll
  for (int s = 0; s < 4; ++s) {
    const float* zp = z + (size_t)myrow * D_DIM + 16 * s + 8 * g;
    float4 f0 = *reinterpret_cast<const float4*>(zp);
    float4 f1 = *reinterpret_cast<const float4*>(zp + 4);
    float xs[8] = {f0.x, f0.y, f0.z, f0.w, f1.x, f1.y, f1.z, f1.w};
#pragma unroll
    for (int j = 0; j < 8; ++j) {
      __bf16 h = (__bf16)xs[j];
      zh[s][j] = h;
      zl[s][j] = (__bf16)(xs[j] - (float)h);
    }
  }

  // --- staging geometry: thread covers (tile t01, code, d-chunk of 8) ---
  const int st_t01 = tid >> 8;          // 0/1
  const int st_c   = (tid >> 3) & 31;   // code in tile
  const int st_ch  = tid & 7;           // d-chunk
  const unsigned st_off = (unsigned)(st_t01 * 16384 + st_ch * 512 + st_c * 16);
  const float* st_g = cb + (size_t)(st_t01 * 32 + st_c) * D_DIM + st_ch * 8;

  float best = FLT_MAX;
  int   bidx = 0;

  // prologue: stage round 0 into buf 0
  float4 p0 = *reinterpret_cast<const float4*>(st_g);
  float4 p1 = *reinterpret_cast<const float4*>(st_g + 4);
  {
    float xs[8] = {p0.x, p0.y, p0.z, p0.w, p1.x, p1.y, p1.z, p1.w};
    bf16x8 hi, lo;
#pragma unroll
    for (int j = 0; j < 8; ++j) {
      __bf16 h = (__bf16)xs[j];
      hi[j] = h;
      lo[j] = (__bf16)(xs[j] - (float)h);
    }
    *reinterpret_cast<bf16x8*>(lds + st_off)        = hi;
    *reinterpret_cast<bf16x8*>(lds + st_off + 8192) = lo;
  }
  __syncthreads();

  const unsigned rd_base = (unsigned)(sp * 16384 + c * 16);

  for (int r = 0; r < NROUND; ++r) {
    const int buf = r & 1;
    // issue next-round global loads early (latency hides under MFMA phase)
    if (r < NROUND - 1) {
      const float* gp = st_g + (size_t)(r + 1) * (64 * D_DIM);
      p0 = *reinterpret_cast<const float4*>(gp);
      p1 = *reinterpret_cast<const float4*>(gp + 4);
    }

    // codebook fragments for my tile (sp): chunk = 2s+g
    const unsigned b0 = (unsigned)buf * 32768u + rd_base;
    bf16x8 ch[4], cl[4];
#pragma unroll
    for (int s = 0; s < 4; ++s) {
      unsigned off = b0 + (unsigned)((2 * s + g) * 512);
      ch[s] = *reinterpret_cast<const bf16x8*>(lds + off);
      cl[s] = *reinterpret_cast<const bf16x8*>(lds + off + 8192);
    }

    f32x16 acc;
#pragma unroll
    for (int i = 0; i < 16; ++i) acc[i] = 0.f;
#pragma unroll
    for (int s = 0; s < 4; ++s) {
      acc = __builtin_amdgcn_mfma_f32_32x32x16_bf16(ch[s], zh[s], acc, 0, 0, 0);
      acc = __builtin_amdgcn_mfma_f32_32x32x16_bf16(ch[s], zl[s], acc, 0, 0, 0);
      acc = __builtin_amdgcn_mfma_f32_32x32x16_bf16(cl[s], zh[s], acc, 0, 0, 0);
    }

    // epilogue: score = r2[k] - 2*dot (z2 dropped: rank-invariant per row).
    // C layout: code=(reg&3)+8*(reg>>2)+4*g, row=lane&31. Ascending k order.
    const int tb = (2 * r + sp) * 32 + 4 * g;
#pragma unroll
    for (int q = 0; q < 4; ++q) {
      float4 rv = *reinterpret_cast<const float4*>(ws + tb + 8 * q);
      float ra[4] = {rv.x, rv.y, rv.z, rv.w};
#pragma unroll
      for (int j = 0; j < 4; ++j) {
        float sc = fmaf(-2.f, acc[4 * q + j], ra[j]);
        int kg = tb + 8 * q + j;
        if (sc < best) { best = sc; bidx = kg; }
      }
    }

    // write staged data for next round into the other buffer
    if (r < NROUND - 1) {
      float xs[8] = {p0.x, p0.y, p0.z, p0.w, p1.x, p1.y, p1.z, p1.w};
      bf16x8 hi, lo;
#pragma unroll
      for (int j = 0; j < 8; ++j) {
        __bf16 h = (__bf16)xs[j];
        hi[j] = h;
        lo[j] = (__bf16)(xs[j] - (float)h);
      }
      unsigned wo = (unsigned)(buf ^ 1) * 32768u + st_off;
      *reinterpret_cast<bf16x8*>(lds + wo)        = hi;
      *reinterpret_cast<bf16x8*>(lds + wo + 8192) = lo;
    }
    __syncthreads();
  }

  // --- merge lane-groups (same row, disjoint code subsets) ---
  {
    float ob = __shfl_xor(best, 32, 64);
    int   oi = __shfl_xor(bidx, 32, 64);
    if (ob < best || (ob == best && oi < bidx)) { best = ob; bidx = oi; }
  }

  // --- merge the two code-split waves per row group via LDS ---
  float* mf  = reinterpret_cast<float*>(lds);          // [8][32]
  int*   mi  = reinterpret_cast<int*>(lds + 1024);     // [8][32]
  int*   mix = reinterpret_cast<int*>(lds + 2048);     // [128]
  if (l < 32) { mf[w * 32 + c] = best; mi[w * 32 + c] = bidx; }
  __syncthreads();
  if (tid < 128) {
    int rgg = tid >> 5, rl = tid & 31;
    float b0 = mf[(2 * rgg) * 32 + rl];     int i0 = mi[(2 * rgg) * 32 + rl];
    float b1 = mf[(2 * rgg + 1) * 32 + rl]; int i1 = mi[(2 * rgg + 1) * 32 + rl];
    int idx = (b1 < b0 || (b1 == b0 && i1 < i0)) ? i1 : i0;
    mix[tid] = idx;
    out[NQ + 2 + rowbase + tid] = (float)idx;
  }
  __syncthreads();

  // --- gather + losses: 4 threads per row ---
  {
    const int row_l = tid >> 2, seg = tid & 3;
    const int idx  = mix[row_l];
    const int grow = rowbase + row_l;
    const float4* qp = reinterpret_cast<const float4*>(cb + (size_t)idx * D_DIM + seg * 16);
    const float4* zp = reinterpret_cast<const float4*>(z + (size_t)grow * D_DIM + seg * 16);
    float4*       op = reinterpret_cast<float4*>(out + (size_t)grow * D_DIM + seg * 16);
    float lp = 0.f;
#pragma unroll
    for (int cc = 0; cc < 4; ++cc) {
      float4 qv = qp[cc], zv = zp[cc];
      op[cc] = qv;
      float dx = zv.x - qv.x, dy = zv.y - qv.y;
      float dz = zv.z - qv.z, dw = zv.w - qv.w;
      lp += (dx * dx + dy * dy) + (dz * dz + dw * dw);
    }
#pragma unroll
    for (int off = 32; off > 0; off >>= 1) lp += __shfl_down(lp, off, 64);
    if (l == 0) atomicAdd(ws + WS_LOSS, lp);
  }
}

// ------------------------------------------------------------ finalize kernel
__global__ void vq_fin(const float* __restrict__ ws, float* __restrict__ out) {
  float mm = ws[WS_LOSS] * (1.0f / (float)(N_ROWS * D_DIM));
  out[NQ]     = mm;  // vq_loss
  out[NQ + 1] = mm;  // commitment_loss
}

// -------------------------------------------------------------------- launch
extern "C" void kernel_launch(void* const* d_in, const int* in_sizes, int n_in,
                              void* d_out, int out_size, void* d_ws, size_t ws_size,
                              hipStream_t stream) {
  (void)in_sizes; (void)n_in; (void)out_size; (void)ws_size;
  const float* z  = (const float*)d_in[0];
  const float* cb = (const float*)d_in[1];
  float* out = (float*)d_out;
  float* ws  = (float*)d_ws;

  vq_prep<<<K_CB / 256, 256, 0, stream>>>(cb, ws);
  vq_main<<<N_ROWS / 128, 512, 0, stream>>>(z, cb, ws, out);
  vq_fin<<<1, 1, 0, stream>>>(ws, out);
}

// Round 5
// 144.718 us; speedup vs baseline: 50.6463x; 1.1946x over previous
//
#include <hip/hip_runtime.h>
#include <cfloat>

// VQ-VAE nearest-codebook via bf16x3 split MFMA, v2:
//   - pre-split codebook (hi/lo bf16) laid out in ws in LDS-tile order
//   - global_load_lds (16B) staging, double-buffered, zero write conflicts
//   - each wave: 128 rows (registers) x 32 codes/round -> 12 MFMA per 2 ds_read
// d_out (f32): [0,NQ) quantized | [NQ] vq_loss | [NQ+1] commitment | [NQ+2,+N) idx
// d_ws  (f32): [0,K) r2 | [K] loss | [8448...) split codebook (2 MB)

typedef __bf16 bf16x8 __attribute__((ext_vector_type(8)));
typedef float  f32x16 __attribute__((ext_vector_type(16)));

constexpr int N_ROWS = 32768;
constexpr int K_CB   = 8192;
constexpr int D_DIM  = 64;
constexpr size_t NQ  = (size_t)N_ROWS * D_DIM;
constexpr int WS_LOSS = K_CB;
constexpr size_t WS_SPLIT_F   = 8448;                       // float offset, 16B aligned
constexpr size_t SPLIT_BYTES  = (size_t)K_CB * D_DIM * 4;   // 2 MB
constexpr size_t WS_NEED      = WS_SPLIT_F * 4 + SPLIT_BYTES;
constexpr int NROUND = K_CB / 256;                          // 32 rounds of 256 codes

#define GLL16(gp, lp)                                                          \
  __builtin_amdgcn_global_load_lds(                                            \
      (const __attribute__((address_space(1))) unsigned int*)(gp),             \
      (__attribute__((address_space(3))) unsigned int*)(lp), 16, 0, 0)

// ---------------------------------------------------------------- prep: r2
__global__ __launch_bounds__(256) void vq_prep(const float* __restrict__ cb,
                                               float* __restrict__ ws) {
  const int k = blockIdx.x * 256 + threadIdx.x;
  if (k == 0) ws[WS_LOSS] = 0.0f;
  const float4* p = reinterpret_cast<const float4*>(cb) + (size_t)k * 16;
  float s0 = 0.f, s1 = 0.f, s2 = 0.f, s3 = 0.f;
#pragma unroll
  for (int j = 0; j < 16; ++j) {
    float4 v = p[j];
    s0 = fmaf(v.x, v.x, s0); s1 = fmaf(v.y, v.y, s1);
    s2 = fmaf(v.z, v.z, s2); s3 = fmaf(v.w, v.w, s3);
  }
  ws[k] = (s0 + s1) + (s2 + s3);
}

// ------------------------------------------------- prep: split codebook in ws
// Layout (bytes, within split region): round r (256 codes) -> 64KB block:
//   tile t(=k>>5 &7)*8192 + h*4096 + ch*512 + c*16, ch=d-chunk of 8, c=k&31.
__global__ __launch_bounds__(256) void vq_split(const float* __restrict__ cb,
                                                float* __restrict__ ws) {
  const int u  = blockIdx.x * 256 + threadIdx.x;   // 65536 threads
  const int k  = u >> 3, ch = u & 7;
  const int r  = k >> 8, t = (k >> 5) & 7, c = k & 31;
  const float* src = cb + (size_t)k * D_DIM + ch * 8;
  float4 f0 = *reinterpret_cast<const float4*>(src);
  float4 f1 = *reinterpret_cast<const float4*>(src + 4);
  float xs[8] = {f0.x, f0.y, f0.z, f0.w, f1.x, f1.y, f1.z, f1.w};
  bf16x8 hi, lo;
#pragma unroll
  for (int j = 0; j < 8; ++j) {
    __bf16 h = (__bf16)xs[j];
    hi[j] = h;
    lo[j] = (__bf16)(xs[j] - (float)h);
  }
  char* base = reinterpret_cast<char*>(ws + WS_SPLIT_F) +
               (size_t)r * 65536 + (size_t)t * 8192 + (size_t)ch * 512 + (size_t)c * 16;
  *reinterpret_cast<bf16x8*>(base)        = hi;
  *reinterpret_cast<bf16x8*>(base + 4096) = lo;
}

// ---------------------------------------------------------------- main kernel
__global__ __launch_bounds__(512, 2) void vq_mfma(const float* __restrict__ z,
                                                  const float* __restrict__ cb,
                                                  float* __restrict__ ws,
                                                  float* __restrict__ out) {
  __shared__ __attribute__((aligned(16))) unsigned char lds[131072];

  const int tid = threadIdx.x;
  const int w = tid >> 6, l = tid & 63;
  const int c = l & 31, g = l >> 5;
  const int rowbase = blockIdx.x * 128;

  // --- z fragments: 4 rowsets x 4 k-steps, hi/lo split, registers forever ---
  bf16x8 zh[4][4], zl[4][4];
#pragma unroll
  for (int q = 0; q < 4; ++q) {
    const float* zr = z + (size_t)(rowbase + q * 32 + c) * D_DIM + 8 * g;
#pragma unroll
    for (int s = 0; s < 4; ++s) {
      float4 f0 = *reinterpret_cast<const float4*>(zr + 16 * s);
      float4 f1 = *reinterpret_cast<const float4*>(zr + 16 * s + 4);
      float xs[8] = {f0.x, f0.y, f0.z, f0.w, f1.x, f1.y, f1.z, f1.w};
#pragma unroll
      for (int j = 0; j < 8; ++j) {
        __bf16 h = (__bf16)xs[j];
        zh[q][s][j] = h;
        zl[q][s][j] = (__bf16)(xs[j] - (float)h);
      }
    }
  }

  // staging source: linear copy of one 64KB round block, 8 chunks x 8KB
  const char* sg = reinterpret_cast<const char*>(ws + WS_SPLIT_F) +
                   (size_t)w * 1024 + (size_t)l * 16;

  // prologue: round 0 -> buf0
#pragma unroll
  for (int j = 0; j < 8; ++j) GLL16(sg + j * 8192, lds + j * 8192 + w * 1024);
  __syncthreads();

  float best[4];
  int   bpack[4];
#pragma unroll
  for (int q = 0; q < 4; ++q) { best[q] = FLT_MAX; bpack[q] = 0; }

  for (int r = 0; r < NROUND; ++r) {
    const int buf = r & 1;
    if (r < NROUND - 1) {
      const char* s2 = sg + (size_t)(r + 1) * 65536;
      unsigned db = (unsigned)(buf ^ 1) * 65536u;
#pragma unroll
      for (int j = 0; j < 8; ++j)
        GLL16(s2 + j * 8192, lds + db + j * 8192 + w * 1024);
    }

    const unsigned rb = (unsigned)buf * 65536u + (unsigned)w * 8192u +
                        (unsigned)g * 512u + (unsigned)c * 16u;
    f32x16 a0, a1, a2, a3;
#pragma unroll
    for (int i = 0; i < 16; ++i) { a0[i] = 0.f; a1[i] = 0.f; a2[i] = 0.f; a3[i] = 0.f; }

#pragma unroll
    for (int s = 0; s < 4; ++s) {
      bf16x8 ca = *reinterpret_cast<const bf16x8*>(lds + rb + s * 1024);
      bf16x8 cb_ = *reinterpret_cast<const bf16x8*>(lds + rb + s * 1024 + 4096);
      a0 = __builtin_amdgcn_mfma_f32_32x32x16_bf16(ca, zh[0][s], a0, 0, 0, 0);
      a1 = __builtin_amdgcn_mfma_f32_32x32x16_bf16(ca, zh[1][s], a1, 0, 0, 0);
      a2 = __builtin_amdgcn_mfma_f32_32x32x16_bf16(ca, zh[2][s], a2, 0, 0, 0);
      a3 = __builtin_amdgcn_mfma_f32_32x32x16_bf16(ca, zh[3][s], a3, 0, 0, 0);
      a0 = __builtin_amdgcn_mfma_f32_32x32x16_bf16(ca, zl[0][s], a0, 0, 0, 0);
      a1 = __builtin_amdgcn_mfma_f32_32x32x16_bf16(ca, zl[1][s], a1, 0, 0, 0);
      a2 = __builtin_amdgcn_mfma_f32_32x32x16_bf16(ca, zl[2][s], a2, 0, 0, 0);
      a3 = __builtin_amdgcn_mfma_f32_32x32x16_bf16(ca, zl[3][s], a3, 0, 0, 0);
      a0 = __builtin_amdgcn_mfma_f32_32x32x16_bf16(cb_, zh[0][s], a0, 0, 0, 0);
      a1 = __builtin_amdgcn_mfma_f32_32x32x16_bf16(cb_, zh[1][s], a1, 0, 0, 0);
      a2 = __builtin_amdgcn_mfma_f32_32x32x16_bf16(cb_, zh[2][s], a2, 0, 0, 0);
      a3 = __builtin_amdgcn_mfma_f32_32x32x16_bf16(cb_, zh[3][s], a3, 0, 0, 0);
    }

    // scores: sc = r2[k] - 2*dot  (z2 dropped: constant per row)
    const float* rp = ws + r * 256 + w * 32 + 4 * g;
    float4 rv0 = *reinterpret_cast<const float4*>(rp);
    float4 rv1 = *reinterpret_cast<const float4*>(rp + 8);
    float4 rv2 = *reinterpret_cast<const float4*>(rp + 16);
    float4 rv3 = *reinterpret_cast<const float4*>(rp + 24);
    float r2v[16] = {rv0.x, rv0.y, rv0.z, rv0.w, rv1.x, rv1.y, rv1.z, rv1.w,
                     rv2.x, rv2.y, rv2.z, rv2.w, rv3.x, rv3.y, rv3.z, rv3.w};
    const int pb = r << 4;
#pragma unroll
    for (int i = 0; i < 16; ++i) {
      float s0 = fmaf(-2.f, a0[i], r2v[i]);
      float s1 = fmaf(-2.f, a1[i], r2v[i]);
      float s2 = fmaf(-2.f, a2[i], r2v[i]);
      float s3 = fmaf(-2.f, a3[i], r2v[i]);
      if (s0 < best[0]) { best[0] = s0; bpack[0] = pb + i; }
      if (s1 < best[1]) { best[1] = s1; bpack[1] = pb + i; }
      if (s2 < best[2]) { best[2] = s2; bpack[2] = pb + i; }
      if (s3 < best[3]) { best[3] = s3; bpack[3] = pb + i; }
    }
    __syncthreads();   // drains prefetch vmcnt; buf^1 ready for next round
  }

  // --- decode packed (round,i) -> global k, then exact-tie merges ---
  int bk[4];
#pragma unroll
  for (int q = 0; q < 4; ++q) {
    int rr = bpack[q] >> 4, i = bpack[q] & 15;
    int cid = (i & 3) + 8 * (i >> 2) + 4 * g;
    bk[q] = rr * 256 + w * 32 + cid;
  }
#pragma unroll
  for (int q = 0; q < 4; ++q) {
    float ob = __shfl_xor(best[q], 32, 64);
    int   ok = __shfl_xor(bk[q], 32, 64);
    if (ob < best[q] || (ob == best[q] && ok < bk[q])) { best[q] = ob; bk[q] = ok; }
  }

  float* fbuf = reinterpret_cast<float*>(lds);          // [8][4][32]
  int*   kbuf = reinterpret_cast<int*>(lds + 4096);     // [8][4][32]
  int*   ibuf = reinterpret_cast<int*>(lds + 8192);     // [128]
  if (l < 32) {
#pragma unroll
    for (int q = 0; q < 4; ++q) {
      fbuf[w * 128 + q * 32 + l] = best[q];
      kbuf[w * 128 + q * 32 + l] = bk[q];
    }
  }
  __syncthreads();

  if (tid < 128) {
    float bb = fbuf[tid];
    int   kk = kbuf[tid];
#pragma unroll
    for (int ww = 1; ww < 8; ++ww) {
      float b2 = fbuf[ww * 128 + tid];
      int   k2 = kbuf[ww * 128 + tid];
      if (b2 < bb || (b2 == bb && k2 < kk)) { bb = b2; kk = k2; }
    }
    ibuf[tid] = kk;
    out[NQ + 2 + rowbase + tid] = (float)kk;
  }
  __syncthreads();

  // --- gather + losses: 4 threads per row ---
  {
    const int row_l = tid >> 2, seg = tid & 3;
    const int idx  = ibuf[row_l];
    const int grow = rowbase + row_l;
    const float4* qp = reinterpret_cast<const float4*>(cb + (size_t)idx * D_DIM + seg * 16);
    const float4* zp = reinterpret_cast<const float4*>(z + (size_t)grow * D_DIM + seg * 16);
    float4*       op = reinterpret_cast<float4*>(out + (size_t)grow * D_DIM + seg * 16);
    float lp = 0.f;
#pragma unroll
    for (int cc = 0; cc < 4; ++cc) {
      float4 qv = qp[cc], zv = zp[cc];
      op[cc] = qv;
      float dx = zv.x - qv.x, dy = zv.y - qv.y;
      float dz = zv.z - qv.z, dw = zv.w - qv.w;
      lp += (dx * dx + dy * dy) + (dz * dz + dw * dw);
    }
#pragma unroll
    for (int off = 32; off > 0; off >>= 1) lp += __shfl_down(lp, off, 64);
    if (l == 0) atomicAdd(ws + WS_LOSS, lp);
  }
}

// ------------------------------------------------- fallback (R4 kernel, used
// only if ws_size can't hold the split codebook)
__global__ __launch_bounds__(512, 2) void vq_main_reg(const float* __restrict__ z,
                                                      const float* __restrict__ cb,
                                                      float* __restrict__ ws,
                                                      float* __restrict__ out) {
  __shared__ __attribute__((aligned(16))) unsigned char lds[65536];
  const int tid = threadIdx.x;
  const int w = tid >> 6, l = tid & 63;
  const int rg = w >> 1, sp = w & 1;
  const int c = l & 31, g = l >> 5;
  const int rowbase = blockIdx.x * 128;
  const int myrow = rowbase + rg * 32 + c;

  bf16x8 zh[4], zl[4];
#pragma unroll
  for (int s = 0; s < 4; ++s) {
    const float* zp = z + (size_t)myrow * D_DIM + 16 * s + 8 * g;
    float4 f0 = *reinterpret_cast<const float4*>(zp);
    float4 f1 = *reinterpret_cast<const float4*>(zp + 4);
    float xs[8] = {f0.x, f0.y, f0.z, f0.w, f1.x, f1.y, f1.z, f1.w};
#pragma unroll
    for (int j = 0; j < 8; ++j) {
      __bf16 h = (__bf16)xs[j];
      zh[s][j] = h;
      zl[s][j] = (__bf16)(xs[j] - (float)h);
    }
  }
  const int st_t01 = tid >> 8;
  const int st_c   = (tid >> 3) & 31;
  const int st_ch  = tid & 7;
  const unsigned st_off = (unsigned)(st_t01 * 16384 + st_ch * 512 + st_c * 16);
  const float* st_g = cb + (size_t)(st_t01 * 32 + st_c) * D_DIM + st_ch * 8;

  float best = FLT_MAX;
  int   bidx = 0;
  float4 p0 = *reinterpret_cast<const float4*>(st_g);
  float4 p1 = *reinterpret_cast<const float4*>(st_g + 4);
  {
    float xs[8] = {p0.x, p0.y, p0.z, p0.w, p1.x, p1.y, p1.z, p1.w};
    bf16x8 hi, lo;
#pragma unroll
    for (int j = 0; j < 8; ++j) {
      __bf16 h = (__bf16)xs[j];
      hi[j] = h; lo[j] = (__bf16)(xs[j] - (float)h);
    }
    *reinterpret_cast<bf16x8*>(lds + st_off)        = hi;
    *reinterpret_cast<bf16x8*>(lds + st_off + 8192) = lo;
  }
  __syncthreads();
  const unsigned rd_base = (unsigned)(sp * 16384 + c * 16);
  for (int r = 0; r < 128; ++r) {
    const int buf = r & 1;
    if (r < 127) {
      const float* gp = st_g + (size_t)(r + 1) * (64 * D_DIM);
      p0 = *reinterpret_cast<const float4*>(gp);
      p1 = *reinterpret_cast<const float4*>(gp + 4);
    }
    const unsigned b0 = (unsigned)buf * 32768u + rd_base;
    bf16x8 ch[4], cl[4];
#pragma unroll
    for (int s = 0; s < 4; ++s) {
      unsigned off = b0 + (unsigned)((2 * s + g) * 512);
      ch[s] = *reinterpret_cast<const bf16x8*>(lds + off);
      cl[s] = *reinterpret_cast<const bf16x8*>(lds + off + 8192);
    }
    f32x16 acc;
#pragma unroll
    for (int i = 0; i < 16; ++i) acc[i] = 0.f;
#pragma unroll
    for (int s = 0; s < 4; ++s) {
      acc = __builtin_amdgcn_mfma_f32_32x32x16_bf16(ch[s], zh[s], acc, 0, 0, 0);
      acc = __builtin_amdgcn_mfma_f32_32x32x16_bf16(ch[s], zl[s], acc, 0, 0, 0);
      acc = __builtin_amdgcn_mfma_f32_32x32x16_bf16(cl[s], zh[s], acc, 0, 0, 0);
    }
    const int tb = (2 * r + sp) * 32 + 4 * g;
#pragma unroll
    for (int q = 0; q < 4; ++q) {
      float4 rv = *reinterpret_cast<const float4*>(ws + tb + 8 * q);
      float ra[4] = {rv.x, rv.y, rv.z, rv.w};
#pragma unroll
      for (int j = 0; j < 4; ++j) {
        float sc = fmaf(-2.f, acc[4 * q + j], ra[j]);
        int kg = tb + 8 * q + j;
        if (sc < best) { best = sc; bidx = kg; }
      }
    }
    if (r < 127) {
      float xs[8] = {p0.x, p0.y, p0.z, p0.w, p1.x, p1.y, p1.z, p1.w};
      bf16x8 hi, lo;
#pragma unroll
      for (int j = 0; j < 8; ++j) {
        __bf16 h = (__bf16)xs[j];
        hi[j] = h; lo[j] = (__bf16)(xs[j] - (float)h);
      }
      unsigned wo = (unsigned)(buf ^ 1) * 32768u + st_off;
      *reinterpret_cast<bf16x8*>(lds + wo)        = hi;
      *reinterpret_cast<bf16x8*>(lds + wo + 8192) = lo;
    }
    __syncthreads();
  }
  {
    float ob = __shfl_xor(best, 32, 64);
    int   oi = __shfl_xor(bidx, 32, 64);
    if (ob < best || (ob == best && oi < bidx)) { best = ob; bidx = oi; }
  }
  float* mf  = reinterpret_cast<float*>(lds);
  int*   mi  = reinterpret_cast<int*>(lds + 1024);
  int*   mix = reinterpret_cast<int*>(lds + 2048);
  if (l < 32) { mf[w * 32 + c] = best; mi[w * 32 + c] = bidx; }
  __syncthreads();
  if (tid < 128) {
    int rgg = tid >> 5, rl = tid & 31;
    float b0 = mf[(2 * rgg) * 32 + rl];     int i0 = mi[(2 * rgg) * 32 + rl];
    float b1 = mf[(2 * rgg + 1) * 32 + rl]; int i1 = mi[(2 * rgg + 1) * 32 + rl];
    int idx = (b1 < b0 || (b1 == b0 && i1 < i0)) ? i1 : i0;
    mix[tid] = idx;
    out[NQ + 2 + rowbase + tid] = (float)idx;
  }
  __syncthreads();
  {
    const int row_l = tid >> 2, seg = tid & 3;
    const int idx  = mix[row_l];
    const int grow = rowbase + row_l;
    const float4* qp = reinterpret_cast<const float4*>(cb + (size_t)idx * D_DIM + seg * 16);
    const float4* zp = reinterpret_cast<const float4*>(z + (size_t)grow * D_DIM + seg * 16);
    float4*       op = reinterpret_cast<float4*>(out + (size_t)grow * D_DIM + seg * 16);
    float lp = 0.f;
#pragma unroll
    for (int cc = 0; cc < 4; ++cc) {
      float4 qv = qp[cc], zv = zp[cc];
      op[cc] = qv;
      float dx = zv.x - qv.x, dy = zv.y - qv.y;
      float dz = zv.z - qv.z, dw = zv.w - qv.w;
      lp += (dx * dx + dy * dy) + (dz * dz + dw * dw);
    }
#pragma unroll
    for (int off = 32; off > 0; off >>= 1) lp += __shfl_down(lp, off, 64);
    if (l == 0) atomicAdd(ws + WS_LOSS, lp);
  }
}

// ------------------------------------------------------------ finalize kernel
__global__ void vq_fin(const float* __restrict__ ws, float* __restrict__ out) {
  float mm = ws[WS_LOSS] * (1.0f / (float)(N_ROWS * D_DIM));
  out[NQ]     = mm;
  out[NQ + 1] = mm;
}

// -------------------------------------------------------------------- launch
extern "C" void kernel_launch(void* const* d_in, const int* in_sizes, int n_in,
                              void* d_out, int out_size, void* d_ws, size_t ws_size,
                              hipStream_t stream) {
  (void)in_sizes; (void)n_in; (void)out_size;
  const float* z  = (const float*)d_in[0];
  const float* cb = (const float*)d_in[1];
  float* out = (float*)d_out;
  float* ws  = (float*)d_ws;

  vq_prep<<<K_CB / 256, 256, 0, stream>>>(cb, ws);
  if (ws_size >= WS_NEED) {
    vq_split<<<256, 256, 0, stream>>>(cb, ws);
    vq_mfma<<<N_ROWS / 128, 512, 0, stream>>>(z, cb, ws, out);
  } else {
    vq_main_reg<<<N_ROWS / 128, 512, 0, stream>>>(z, cb, ws, out);
  }
  vq_fin<<<1, 1, 0, stream>>>(ws, out);
}